// Round 17
// baseline (103.090 us; speedup 1.0000x reference)
//
#include <hip/hip_runtime.h>
#include <stdint.h>

// DNAS_DeformAxialDW: out = x + axial-deform-DW-conv_H(x) + axial-deform-DW-conv_W(x)
// Scalar fractional dilation r => each 7-tap conv folds into 13 integer taps with
// per-channel effective weights (precomputed into d_ws by taps_kernel).
//
// R11 106; R13 213 (but proved side reads = 85% of conflict cycles);
// R15 98.5 BEST (persistent half-plane, per-row DMA, padded stride, vmcnt(6));
// R16 102.9 circular buffer: slot-wrap VALU ate the occupancy gain. REVERTED.
// R17: kill the side-quad ds_reads entirely: BLOCK=512, wave=row-group,
//      lane=cq (56 active) => neighbor quads live in sibling LANES of the same
//      wave when the center row is streamed. 12 ds_bpermute (shuffle, no bank
//      conflicts) replace 8 ds_read_b128/thread-tile; every out-of-wave shuffle
//      coincides with a zero-pad edge. Reads 22->14; conflicts should collapse.

namespace {
constexpr int B = 8, C = 128, H = 224, W = 224;
constexpr int KT = 7;              // original taps
constexpr int M  = 6;              // max |integer offset| (r in [1,2])
constexpr int NT = 2 * M + 1;      // 13 effective integer taps
constexpr int TH = 16;             // output rows per tile
constexpr int NTPB = 7;            // tiles per block (half-plane: 112 rows)
constexpr int SROWS = TH + 2 * M;  // 28 staged rows
constexpr int WQ = W / 4;          // 56 quads per row
constexpr int BLOCK = 512;         // 8 waves; wave = row-group, lane = cq (<56)
constexpr int RPT = 2;             // output rows per thread
constexpr int WROWS = RPT + 2 * M; // 14 window rows per thread
constexpr int RSTRIDE = 228;       // padded LDS row stride (floats), 16B aligned
constexpr int BUF_FLOATS = SROWS * RSTRIDE;   // 6384 floats = 25,536 B
constexpr int LDS_FLOATS = 2 * BUF_FLOATS;    // 51,072 B -> 3 blocks/CU
constexpr int ZOFF = 2 * C * NT;   // zeros region offset in d_ws (floats) = 3328
}

typedef __attribute__((address_space(3))) uint32_t lds_u32;
typedef __attribute__((address_space(1))) const uint32_t gbl_u32;

// Fold bilinear fractional taps into integer-offset effective weights; also
// zero-fill the 256-float OOB source region at taps+ZOFF.
__global__ void taps_kernel(const float* __restrict__ wh, const float* __restrict__ ww,
                            const float* __restrict__ r, float* __restrict__ taps) {
    int c = threadIdx.x;
    if (c >= C) return;
    taps[ZOFF + c]     = 0.f;   // zero region for OOB staging reads
    taps[ZOFF + C + c] = 0.f;
    float rv = fmaxf(r[0], 1.0f);  // jnp.clip(r, 1.0)
    float eh[NT], ew[NT];
    for (int j = 0; j < NT; ++j) { eh[j] = 0.f; ew[j] = 0.f; }
    for (int i = 0; i < KT; ++i) {
        float kpos  = (float)(i - KT / 2);
        float delta = kpos * rv;
        float d0f   = floorf(delta);
        float fr    = delta - d0f;
        int   j0    = (int)d0f + M;
        float whv = wh[c * KT + i];
        float wwv = ww[c * KT + i];
        if (j0 >= 0 && j0 < NT)         { eh[j0]   += (1.f - fr) * whv; ew[j0]   += (1.f - fr) * wwv; }
        if (j0 + 1 >= 0 && j0 + 1 < NT) { eh[j0+1] += fr * whv;         ew[j0+1] += fr * wwv; }
    }
    for (int j = 0; j < NT; ++j) {
        taps[c * NT + j]          = eh[j];
        taps[C * NT + c * NT + j] = ew[j];
    }
}

__global__ __launch_bounds__(BLOCK) void deform_axial_kernel(
    const float* __restrict__ x, const float* __restrict__ taps,
    float* __restrict__ out) {
    __shared__ float lds[LDS_FLOATS];   // 51,072 B -> 3 blocks/CU

    const int bid   = blockIdx.x;        // 0..2047
    const int p     = bid >> 1;          // plane (b*C + c) -- block-uniform
    const int half  = bid & 1;           // 0: rows 0..111, 1: rows 112..223
    const int hbase = half * (H / 2);
    const int c     = p & (C - 1);       // uniform -> taps via scalar loads
    const int tid   = threadIdx.x;
    const int wave  = tid >> 6;          // row group 0..7
    const int lane  = tid & 63;          // cq (valid < 56)

    const long base = (long)p * (H * W);
    const float* __restrict__ xp = x + base;

    // per-channel effective taps: block-uniform address -> SGPRs
    float eh[NT], ew[NT];
    const float* __restrict__ ehp = taps + c * NT;
    const float* __restrict__ ewp = taps + C * NT + c * NT;
#pragma unroll
    for (int j = 0; j < NT; ++j) { eh[j] = ehp[j]; ew[j] = ewp[j]; }
    const float ws6 = ew[6] + 1.0f;   // center W-tap with identity folded in
    // drain any vector loads so manual vmcnt bookkeeping starts from 0
    asm volatile("s_waitcnt vmcnt(0)" ::: "memory");

    const float* zbase = taps + ZOFF + lane * 4;  // per-lane 16B zero slot
    float* const buf0 = lds;
    float* const buf1 = lds + BUF_FLOATS;

    // ---- stage tile t's 28-row window: 1 DMA per row, 4 rows/wave (32 issues,
    // 4 benign duplicates). 56 active lanes x 16B at wave-uniform padded base.
    auto STAGE = [&](float* bufb, int t) {
        const int h0 = hbase + t * TH;
#pragma unroll
        for (int k = 0; k < 4; ++k) {
            int row = k * 8 + wave;                   // 0..31, wave-uniform
            if (row >= SROWS) row = wave;             // dup of own k=0 row (benign)
            const int grow = h0 - M + row;
            const bool vr  = (unsigned)grow < (unsigned)H;
            const float* src = vr ? (xp + grow * W + lane * 4) : zbase;
            float* dst = bufb + row * RSTRIDE;        // wave-uniform
            if (lane < 56) {
                __builtin_amdgcn_global_load_lds((gbl_u32*)src, (lds_u32*)dst, 16, 0, 0);
            }
        }
    };

    auto BAR = []() {
        asm volatile("" ::: "memory");
        __builtin_amdgcn_s_barrier();
        asm volatile("" ::: "memory");
    };

    const int cq = lane;            // column quad (valid < 56)
    const int r0 = wave * RPT;      // first output row within tile (0..14)
    const float4 zero4 = make_float4(0.f, 0.f, 0.f, 0.f);

    // ---- compute tile t (lanes < 56 only), store (2 stores/thread) ----
    auto COMPUTE = [&](const float* ldsb, int t) {
        const int h0 = hbase + t * TH;
        float4 acc[RPT];
#pragma unroll
        for (int k = 0; k < RPT; ++k) acc[k] = zero4;

#pragma unroll
        for (int s = 0; s < WROWS; ++s) {
            const float4 q = *reinterpret_cast<const float4*>(&ldsb[(r0 + s) * RSTRIDE + cq * 4]);

            // H-axis: streamed row s is tap j = s-k for output row k
#pragma unroll
            for (int k = 0; k < RPT; ++k) {
                const int j = s - k;
                if (j >= 0 && j < NT) {
                    const float wgt = eh[j];
                    acc[k].x = fmaf(wgt, q.x, acc[k].x);
                    acc[k].y = fmaf(wgt, q.y, acc[k].y);
                    acc[k].z = fmaf(wgt, q.z, acc[k].z);
                    acc[k].w = fmaf(wgt, q.w, acc[k].w);
                }
            }

            // center row for output k = s - M: W-conv (identity folded into ws6).
            // Neighbor quads come from sibling LANES via shuffle (row == wave
            // mapping => same-row neighbors are always in this wave; every
            // out-of-wave source coincides with a zero-pad edge and is masked).
            if (s >= M && s < M + RPT) {
                const int k = s - M;
                float4& a = acc[k];

                float4 qm1, qp1;
                qm1.x = __shfl(q.x, lane - 1); qm1.y = __shfl(q.y, lane - 1);
                qm1.z = __shfl(q.z, lane - 1); qm1.w = __shfl(q.w, lane - 1);
                qp1.x = __shfl(q.x, lane + 1); qp1.y = __shfl(q.y, lane + 1);
                qp1.z = __shfl(q.z, lane + 1); qp1.w = __shfl(q.w, lane + 1);
                float qm2z = __shfl(q.z, lane - 2);
                float qm2w = __shfl(q.w, lane - 2);
                float qp2x = __shfl(q.x, lane + 2);
                float qp2y = __shfl(q.y, lane + 2);
                if (cq < 1)      qm1 = zero4;
                if (cq < 2)      { qm2z = 0.f; qm2w = 0.f; }
                if (cq > WQ - 2) qp1 = zero4;
                if (cq > WQ - 3) { qp2x = 0.f; qp2y = 0.f; }

                {   // d = -2: 3 FMAs
                    a.x = fmaf(ew[0], qm2z, a.x);
                    a.x = fmaf(ew[1], qm2w, a.x);
                    a.y = fmaf(ew[0], qm2w, a.y);
                }
                {   // d = -1: 15 FMAs (j = m - e + 2)
                    a.x = fmaf(ew[2], qm1.x, a.x); a.y = fmaf(ew[1], qm1.x, a.y); a.z = fmaf(ew[0], qm1.x, a.z);
                    a.x = fmaf(ew[3], qm1.y, a.x); a.y = fmaf(ew[2], qm1.y, a.y); a.z = fmaf(ew[1], qm1.y, a.z); a.w = fmaf(ew[0], qm1.y, a.w);
                    a.x = fmaf(ew[4], qm1.z, a.x); a.y = fmaf(ew[3], qm1.z, a.y); a.z = fmaf(ew[2], qm1.z, a.z); a.w = fmaf(ew[1], qm1.z, a.w);
                    a.x = fmaf(ew[5], qm1.w, a.x); a.y = fmaf(ew[4], qm1.w, a.y); a.z = fmaf(ew[3], qm1.w, a.z); a.w = fmaf(ew[2], qm1.w, a.w);
                }
                {   // d = 0: 16 FMAs (j = m - e + 6), diagonal uses ws6 = ew[6]+1
                    a.x = fmaf(ws6,   q.x, a.x); a.y = fmaf(ew[5], q.x, a.y); a.z = fmaf(ew[4], q.x, a.z); a.w = fmaf(ew[3], q.x, a.w);
                    a.x = fmaf(ew[7], q.y, a.x); a.y = fmaf(ws6,   q.y, a.y); a.z = fmaf(ew[5], q.y, a.z); a.w = fmaf(ew[4], q.y, a.w);
                    a.x = fmaf(ew[8], q.z, a.x); a.y = fmaf(ew[7], q.z, a.y); a.z = fmaf(ws6,   q.z, a.z); a.w = fmaf(ew[5], q.z, a.w);
                    a.x = fmaf(ew[9], q.w, a.x); a.y = fmaf(ew[8], q.w, a.y); a.z = fmaf(ew[7], q.w, a.z); a.w = fmaf(ws6,   q.w, a.w);
                }
                {   // d = +1: 15 FMAs (j = m - e + 10)
                    a.x = fmaf(ew[10], qp1.x, a.x); a.y = fmaf(ew[9],  qp1.x, a.y); a.z = fmaf(ew[8],  qp1.x, a.z); a.w = fmaf(ew[7],  qp1.x, a.w);
                    a.x = fmaf(ew[11], qp1.y, a.x); a.y = fmaf(ew[10], qp1.y, a.y); a.z = fmaf(ew[9],  qp1.y, a.z); a.w = fmaf(ew[8],  qp1.y, a.w);
                    a.x = fmaf(ew[12], qp1.z, a.x); a.y = fmaf(ew[11], qp1.z, a.y); a.z = fmaf(ew[10], qp1.z, a.z); a.w = fmaf(ew[9],  qp1.z, a.w);
                                                    a.y = fmaf(ew[12], qp1.w, a.y); a.z = fmaf(ew[11], qp1.w, a.z); a.w = fmaf(ew[10], qp1.w, a.w);
                }
                {   // d = +2: 3 FMAs (j = m - e + 14)
                    a.z = fmaf(ew[12], qp2x, a.z);
                    a.w = fmaf(ew[11], qp2x, a.w);
                    a.w = fmaf(ew[12], qp2y, a.w);
                }
            }
        }

        float* outp = out + base + (long)(h0 + r0) * W + cq * 4;
#pragma unroll
        for (int k = 0; k < RPT; ++k) {
            *reinterpret_cast<float4*>(outp + k * W) = acc[k];
        }
    };

    // ---- pipeline: per-wave vmem order [4 DMA][4 DMA] [2 st][4 DMA][2 st]... ----
    STAGE(buf0, 0);                                       // S0
    STAGE(buf1, 1);                                       // S1
    asm volatile("s_waitcnt vmcnt(4)" ::: "memory");      // S0 done (S1 in flight)
    BAR();
    if (lane < 56) COMPUTE(buf0, 0);                      // + stores(0)
    BAR();

#pragma unroll
    for (int t = 1; t <= NTPB - 2; ++t) {                 // t = 1..5
        STAGE((t & 1) ? buf0 : buf1, t + 1);              // S(t+1) -> buf[(t+1)&1]
        // newest 6 = stores(t-1)[2] + S(t+1)[4]  =>  S(t) complete
        asm volatile("s_waitcnt vmcnt(6)" ::: "memory");
        BAR();
        if (lane < 56) COMPUTE((t & 1) ? buf1 : buf0, t); // + stores(t)
        BAR();
    }

    // newest 2 = stores(5)  =>  S6 complete
    asm volatile("s_waitcnt vmcnt(2)" ::: "memory");
    BAR();
    if (lane < 56) COMPUTE(buf0, NTPB - 1);               // tile 6 from buf0
}

extern "C" void kernel_launch(void* const* d_in, const int* in_sizes, int n_in,
                              void* d_out, int out_size, void* d_ws, size_t ws_size,
                              hipStream_t stream) {
    const float* x  = (const float*)d_in[0];
    const float* wh = (const float*)d_in[1];
    const float* ww = (const float*)d_in[2];
    const float* r  = (const float*)d_in[3];
    float* out  = (float*)d_out;
    float* taps = (float*)d_ws;  // needs (2*C*NT + 256)*4 = 14,336 bytes

    hipLaunchKernelGGL(taps_kernel, dim3(1), dim3(C), 0, stream, wh, ww, r, taps);
    hipLaunchKernelGGL(deform_axial_kernel, dim3(2 * B * C), dim3(BLOCK),
                       0, stream, x, taps, out);
}

// Round 18
// 90.802 us; speedup vs baseline: 1.1353x; 1.1353x over previous
//
#include <hip/hip_runtime.h>
#include <stdint.h>

// DNAS_DeformAxialDW: out = x + axial-deform-DW-conv_H(x) + axial-deform-DW-conv_W(x)
// Scalar fractional dilation r => each 7-tap conv folds into 13 integer taps with
// per-channel effective weights (precomputed into d_ws by taps_kernel).
//
// R15 98.5 BEST (persistent half-plane, per-row DMA dbuf, counted vmcnt).
// R16 102.9 circular buffer (slot-wrap VALU). R17 103 shuffle W-conv: conflicts
//     1.686e7->1.95e6 but time flat => LDS pipe NOT critical path; residual is
//     per-tile stage/wait/barrier serialization on the compute waves.
// R18: producer-consumer wave split. BLOCK=512: waves 0-6 = R15 compute body
//      (threads 0-447, same mapping); wave 7 = producer issuing all 28 row-DMAs
//      for tile t+1 into buf[(t+1)&1] and absorbing vmcnt(0) while consumers
//      compute tile t from buf[t&1]. Consumers: no vmem waits, no stage issue,
//      ONE barrier per tile. LDS 51KB -> 3 blk/CU x 8 waves = 24 waves.

namespace {
constexpr int B = 8, C = 128, H = 224, W = 224;
constexpr int KT = 7;              // original taps
constexpr int M  = 6;              // max |integer offset| (r in [1,2])
constexpr int NT = 2 * M + 1;      // 13 effective integer taps
constexpr int TH = 16;             // output rows per tile
constexpr int NTPB = 7;            // tiles per block (half-plane: 112 rows)
constexpr int SROWS = TH + 2 * M;  // 28 staged rows
constexpr int WQ = W / 4;          // 56 quads per row
constexpr int BLOCK = 512;         // 7 consumer waves (448 thr) + 1 producer wave
constexpr int NCONS = 448;         // consumer threads
constexpr int RPT = 2;             // output rows per thread
constexpr int WROWS = RPT + 2 * M; // 14 window rows per thread
constexpr int RSTRIDE = 228;       // padded LDS row stride (floats), 16B aligned
constexpr int BUF_FLOATS = SROWS * RSTRIDE;   // 6384 floats = 25,536 B
constexpr int LDS_FLOATS = 2 * BUF_FLOATS;    // 51,072 B -> 3 blocks/CU
constexpr int ZOFF = 2 * C * NT;   // zeros region offset in d_ws (floats) = 3328
}

typedef __attribute__((address_space(3))) uint32_t lds_u32;
typedef __attribute__((address_space(1))) const uint32_t gbl_u32;

// Fold bilinear fractional taps into integer-offset effective weights; also
// zero-fill the 256-float OOB source region at taps+ZOFF.
__global__ void taps_kernel(const float* __restrict__ wh, const float* __restrict__ ww,
                            const float* __restrict__ r, float* __restrict__ taps) {
    int c = threadIdx.x;
    if (c >= C) return;
    taps[ZOFF + c]     = 0.f;   // zero region for OOB staging reads
    taps[ZOFF + C + c] = 0.f;
    float rv = fmaxf(r[0], 1.0f);  // jnp.clip(r, 1.0)
    float eh[NT], ew[NT];
    for (int j = 0; j < NT; ++j) { eh[j] = 0.f; ew[j] = 0.f; }
    for (int i = 0; i < KT; ++i) {
        float kpos  = (float)(i - KT / 2);
        float delta = kpos * rv;
        float d0f   = floorf(delta);
        float fr    = delta - d0f;
        int   j0    = (int)d0f + M;
        float whv = wh[c * KT + i];
        float wwv = ww[c * KT + i];
        if (j0 >= 0 && j0 < NT)         { eh[j0]   += (1.f - fr) * whv; ew[j0]   += (1.f - fr) * wwv; }
        if (j0 + 1 >= 0 && j0 + 1 < NT) { eh[j0+1] += fr * whv;         ew[j0+1] += fr * wwv; }
    }
    for (int j = 0; j < NT; ++j) {
        taps[c * NT + j]          = eh[j];
        taps[C * NT + c * NT + j] = ew[j];
    }
}

__global__ __launch_bounds__(BLOCK) void deform_axial_kernel(
    const float* __restrict__ x, const float* __restrict__ taps,
    float* __restrict__ out) {
    __shared__ float lds[LDS_FLOATS];   // 51,072 B -> 3 blocks/CU

    const int bid   = blockIdx.x;        // 0..2047
    const int p     = bid >> 1;          // plane (b*C + c) -- block-uniform
    const int half  = bid & 1;           // 0: rows 0..111, 1: rows 112..223
    const int hbase = half * (H / 2);
    const int c     = p & (C - 1);       // uniform -> taps via scalar loads
    const int tid   = threadIdx.x;
    const int wave  = tid >> 6;
    const int lane  = tid & 63;
    const bool producer = (wave == 7);   // wave-uniform role split

    const long base = (long)p * (H * W);
    const float* __restrict__ xp = x + base;

    // per-channel effective taps: block-uniform address -> SGPRs
    float eh[NT], ew[NT];
    const float* __restrict__ ehp = taps + c * NT;
    const float* __restrict__ ewp = taps + C * NT + c * NT;
#pragma unroll
    for (int j = 0; j < NT; ++j) { eh[j] = ehp[j]; ew[j] = ewp[j]; }
    const float ws6 = ew[6] + 1.0f;   // center W-tap with identity folded in
    // drain so the producer's vmcnt bookkeeping starts from 0 outstanding
    asm volatile("s_waitcnt vmcnt(0)" ::: "memory");

    const float* zbase = taps + ZOFF + lane * 4;  // per-lane 16B zero slot
    float* const buf0 = lds;
    float* const buf1 = lds + BUF_FLOATS;

    // ---- producer: stage tile t's 28-row window, 1 DMA per row (28 instrs) ----
    auto STAGE = [&](float* bufb, int t) {
        const int h0 = hbase + t * TH;
#pragma unroll
        for (int row = 0; row < SROWS; ++row) {
            const int grow = h0 - M + row;
            const bool vr  = (unsigned)grow < (unsigned)H;
            const float* src = vr ? (xp + grow * W + lane * 4) : zbase;
            float* dst = bufb + row * RSTRIDE;        // wave-uniform
            if (lane < 56) {
                __builtin_amdgcn_global_load_lds((gbl_u32*)src, (lds_u32*)dst, 16, 0, 0);
            }
        }
    };

    auto BAR = []() {
        asm volatile("" ::: "memory");
        __builtin_amdgcn_s_barrier();
        asm volatile("" ::: "memory");
    };

    // consumer geometry (threads 0..447; R15 mapping)
    const int cq = tid % WQ;        // column quad 0..55
    const int rg = tid / WQ;        // row group 0..7 (producer wave: ignored)
    const int r0 = rg * RPT;        // first output row within tile
    const float4 zero4 = make_float4(0.f, 0.f, 0.f, 0.f);

    // ---- consumer: compute tile t from buffer, store (2 stores/thread) ----
    auto COMPUTE = [&](const float* ldsb, int t) {
        const int h0 = hbase + t * TH;
        float4 acc[RPT];
#pragma unroll
        for (int k = 0; k < RPT; ++k) acc[k] = zero4;

#pragma unroll
        for (int s = 0; s < WROWS; ++s) {
            const float4 q = *reinterpret_cast<const float4*>(&ldsb[(r0 + s) * RSTRIDE + cq * 4]);

            // H-axis: streamed row s is tap j = s-k for output row k
#pragma unroll
            for (int k = 0; k < RPT; ++k) {
                const int j = s - k;
                if (j >= 0 && j < NT) {
                    const float wgt = eh[j];
                    acc[k].x = fmaf(wgt, q.x, acc[k].x);
                    acc[k].y = fmaf(wgt, q.y, acc[k].y);
                    acc[k].z = fmaf(wgt, q.z, acc[k].z);
                    acc[k].w = fmaf(wgt, q.w, acc[k].w);
                }
            }

            // center row for output k = s - M: W-conv (identity folded into ws6).
            // Source quad d (-2..2), elem m -> acc elem e uses tap j = 4d+m-e+6.
            if (s >= M && s < M + RPT) {
                const int k = s - M;
                const float* crow = &ldsb[(r0 + s) * RSTRIDE];
                float4& a = acc[k];

                {   // d = -2: 3 FMAs
                    const float4 qd = (cq >= 2) ? *reinterpret_cast<const float4*>(crow + (cq - 2) * 4) : zero4;
                    a.x = fmaf(ew[0], qd.z, a.x);
                    a.x = fmaf(ew[1], qd.w, a.x);
                    a.y = fmaf(ew[0], qd.w, a.y);
                }
                {   // d = -1: 15 FMAs (j = m - e + 2)
                    const float4 qd = (cq >= 1) ? *reinterpret_cast<const float4*>(crow + (cq - 1) * 4) : zero4;
                    a.x = fmaf(ew[2], qd.x, a.x); a.y = fmaf(ew[1], qd.x, a.y); a.z = fmaf(ew[0], qd.x, a.z);
                    a.x = fmaf(ew[3], qd.y, a.x); a.y = fmaf(ew[2], qd.y, a.y); a.z = fmaf(ew[1], qd.y, a.z); a.w = fmaf(ew[0], qd.y, a.w);
                    a.x = fmaf(ew[4], qd.z, a.x); a.y = fmaf(ew[3], qd.z, a.y); a.z = fmaf(ew[2], qd.z, a.z); a.w = fmaf(ew[1], qd.z, a.w);
                    a.x = fmaf(ew[5], qd.w, a.x); a.y = fmaf(ew[4], qd.w, a.y); a.z = fmaf(ew[3], qd.w, a.z); a.w = fmaf(ew[2], qd.w, a.w);
                }
                {   // d = 0: 16 FMAs (j = m - e + 6), diagonal uses ws6 = ew[6]+1
                    a.x = fmaf(ws6,   q.x, a.x); a.y = fmaf(ew[5], q.x, a.y); a.z = fmaf(ew[4], q.x, a.z); a.w = fmaf(ew[3], q.x, a.w);
                    a.x = fmaf(ew[7], q.y, a.x); a.y = fmaf(ws6,   q.y, a.y); a.z = fmaf(ew[5], q.y, a.z); a.w = fmaf(ew[4], q.y, a.w);
                    a.x = fmaf(ew[8], q.z, a.x); a.y = fmaf(ew[7], q.z, a.y); a.z = fmaf(ws6,   q.z, a.z); a.w = fmaf(ew[5], q.z, a.w);
                    a.x = fmaf(ew[9], q.w, a.x); a.y = fmaf(ew[8], q.w, a.y); a.z = fmaf(ew[7], q.w, a.z); a.w = fmaf(ws6,   q.w, a.w);
                }
                {   // d = +1: 15 FMAs (j = m - e + 10)
                    const float4 qd = (cq <= WQ - 2) ? *reinterpret_cast<const float4*>(crow + (cq + 1) * 4) : zero4;
                    a.x = fmaf(ew[10], qd.x, a.x); a.y = fmaf(ew[9],  qd.x, a.y); a.z = fmaf(ew[8],  qd.x, a.z); a.w = fmaf(ew[7],  qd.x, a.w);
                    a.x = fmaf(ew[11], qd.y, a.x); a.y = fmaf(ew[10], qd.y, a.y); a.z = fmaf(ew[9],  qd.y, a.z); a.w = fmaf(ew[8],  qd.y, a.w);
                    a.x = fmaf(ew[12], qd.z, a.x); a.y = fmaf(ew[11], qd.z, a.y); a.z = fmaf(ew[10], qd.z, a.z); a.w = fmaf(ew[9],  qd.z, a.w);
                                                   a.y = fmaf(ew[12], qd.w, a.y); a.z = fmaf(ew[11], qd.w, a.z); a.w = fmaf(ew[10], qd.w, a.w);
                }
                {   // d = +2: 3 FMAs (j = m - e + 14)
                    const float4 qd = (cq <= WQ - 3) ? *reinterpret_cast<const float4*>(crow + (cq + 2) * 4) : zero4;
                    a.z = fmaf(ew[12], qd.x, a.z);
                    a.w = fmaf(ew[11], qd.x, a.w);
                    a.w = fmaf(ew[12], qd.y, a.w);
                }
            }
        }

        float* outp = out + base + (long)(h0 + r0) * W + cq * 4;
#pragma unroll
        for (int k = 0; k < RPT; ++k) {
            *reinterpret_cast<float4*>(outp + k * W) = acc[k];
        }
    };

    // ---- producer/consumer pipeline: ONE barrier per tile ----
    // Invariant at tile-t barrier entry: buf[t&1] holds window t, complete.
    if (producer) {
        STAGE(buf0, 0);
        asm volatile("s_waitcnt vmcnt(0)" ::: "memory");  // window 0 landed
    }
    BAR();

#pragma unroll
    for (int t = 0; t < NTPB; ++t) {
        if (producer) {
            if (t + 1 < NTPB) {
                STAGE((t & 1) ? buf0 : buf1, t + 1);      // write buffer consumers
                                                          // are NOT reading this tile
                asm volatile("s_waitcnt vmcnt(0)" ::: "memory");  // producer-only wait
            }
        } else {
            COMPUTE((t & 1) ? buf1 : buf0, t);            // read buf[t&1] + stores
        }
        BAR();                                            // window t+1 ready; reads done
    }
}

extern "C" void kernel_launch(void* const* d_in, const int* in_sizes, int n_in,
                              void* d_out, int out_size, void* d_ws, size_t ws_size,
                              hipStream_t stream) {
    const float* x  = (const float*)d_in[0];
    const float* wh = (const float*)d_in[1];
    const float* ww = (const float*)d_in[2];
    const float* r  = (const float*)d_in[3];
    float* out  = (float*)d_out;
    float* taps = (float*)d_ws;  // needs (2*C*NT + 256)*4 = 14,336 bytes

    hipLaunchKernelGGL(taps_kernel, dim3(1), dim3(C), 0, stream, wh, ww, r, taps);
    hipLaunchKernelGGL(deform_axial_kernel, dim3(2 * B * C), dim3(BLOCK),
                       0, stream, x, taps, out);
}